// Round 4
// baseline (6612.970 us; speedup 1.0000x reference)
//
#include <hip/hip_runtime.h>
#include <hip/hip_bf16.h>

// Problem constants (reference file)
#define D   1024
#define H   16
#define DH  64
#define FF  4096
#define E   4
#define BSZ 2
#define TT  2048
#define NTOK (BSZ*TT)   // 4096 tokens

typedef __hip_bfloat16 bf16;

__device__ __forceinline__ float us2f(unsigned short u) {
    return __uint_as_float(((unsigned int)u) << 16);  // bf16 -> f32 is exact
}

// ---------------------------------------------------------------------------
// Dtype probe: decide whether float-class inputs are packed bf16 (flag=1) or
// float32 (flag=0). For f32 data the LOW 16 bits of each 32-bit word are
// random mantissa bits -> ~30% have bf16-exponent >= 0x5A ("wild"). For bf16
// data every 16-bit half is a sane N(0,1)-ish value -> 0 wild.
// Pure bit tests (immune to fast-math NaN folding). Also zero-inits cnt[].
// R3 evidence: this probe correctly detected f32 inputs (NaN disappeared).
// ---------------------------------------------------------------------------
__global__ __launch_bounds__(64) void probe_k(const unsigned* __restrict__ xw,
                                              int* __restrict__ meta) {
    const int lane = threadIdx.x;
    int wild = 0;
    for (int i = 0; i < 32; i++) {
        unsigned u = xw[lane * 32 + i];
        unsigned lo = u & 0xFFFFu;
        if ((lo & 0x7F80u) >= 0x5A00u) wild++;   // |bf16(lo)| >= ~2^53 or NaN/Inf
    }
#pragma unroll
    for (int m = 32; m > 0; m >>= 1) wild += __shfl_xor(wild, m, 64);
    if (lane == 0) meta[4] = (wild < 64) ? 1 : 0;   // 1 = bf16 inputs, 0 = f32
    if (lane < 4) meta[lane] = 0;                   // expert counters
}

// ---------------------------------------------------------------------------
// x -> f32 staging (dual dtype), 4 elems/thread
// ---------------------------------------------------------------------------
__global__ __launch_bounds__(256) void convert_k(const void* __restrict__ in,
                                                 float* __restrict__ out,
                                                 const int* __restrict__ meta) {
    const int i = blockIdx.x * 256 + threadIdx.x;   // group of 4 elems
    if (meta[4]) {
        ushort4 u = ((const ushort4*)in)[i];
        ((float4*)out)[i] = make_float4(us2f(u.x), us2f(u.y), us2f(u.z), us2f(u.w));
    } else {
        ((float4*)out)[i] = ((const float4*)in)[i];
    }
}

// ---------------------------------------------------------------------------
// Tiled GEMM: C[M,N] = A[M,K](f32 ws) * B[K,N](input dtype) + bias(input dtype)
//   optional row gather/scatter (expert buckets), relu, f32 residual.
//   64x64 tile, BK=16, 256 threads, 4x4 micro-tile, fp32 accumulate.
//   C is always written as f32 (reference output dtype is float32).
// ---------------------------------------------------------------------------
__global__ __launch_bounds__(256) void sgemm_k(
    const float* __restrict__ A, const void* __restrict__ Bw,
    const void* __restrict__ bias, float* __restrict__ C,
    const float* __restrict__ resid, const int* __restrict__ rowlist,
    const int* __restrict__ rowcnt, const int* __restrict__ meta,
    int M, int N, int K, int relu)
{
    const int bfm = meta[4];
    const int e = blockIdx.z;
    const int cnt = rowcnt ? rowcnt[e] : M;
    const int m0 = blockIdx.y * 64;
    if (m0 >= cnt) return;                       // empty expert tile (block-uniform)
    const int n0 = blockIdx.x * 64;
    const int* lp = rowlist ? (rowlist + e * NTOK) : nullptr;

    __shared__ float As[16][64];   // As[k][m]
    __shared__ float Bs[16][64];   // Bs[k][n]

    const int tid = threadIdx.x;
    // A staging: 64 rows x 16 k, 4 consecutive k per thread
    const int ar = tid >> 2;
    const int ac = (tid & 3) << 2;
    const int r_a = m0 + ar;
    const bool avalid = (r_a < cnt);
    const int atok = avalid ? (lp ? lp[r_a] : r_a) : 0;
    const float* af = A + (size_t)atok * K + ac;
    // B staging: 16 k x 64 n, 4 consecutive n per thread
    const int br = tid >> 4;
    const int bc = (tid & 15) << 2;
    size_t boff = (size_t)e * K * N + (size_t)br * N + (n0 + bc);

    const int tx = tid & 15, ty = tid >> 4;
    float acc[4][4];
#pragma unroll
    for (int i = 0; i < 4; i++)
#pragma unroll
        for (int j = 0; j < 4; j++) acc[i][j] = 0.f;

    for (int k0 = 0; k0 < K; k0 += 16) {
        float4 av = make_float4(0.f, 0.f, 0.f, 0.f);
        if (avalid) av = *(const float4*)af;
        float4 bv;
        if (bfm) {
            ushort4 bu = *(const ushort4*)((const unsigned short*)Bw + boff);
            bv = make_float4(us2f(bu.x), us2f(bu.y), us2f(bu.z), us2f(bu.w));
        } else {
            bv = *(const float4*)((const float*)Bw + boff);
        }
        As[ac + 0][ar] = av.x; As[ac + 1][ar] = av.y;
        As[ac + 2][ar] = av.z; As[ac + 3][ar] = av.w;
        *(float4*)&Bs[br][bc] = bv;
        __syncthreads();
#pragma unroll
        for (int kk = 0; kk < 16; kk++) {
            float4 a4 = *(const float4*)&As[kk][ty << 2];
            float4 b4 = *(const float4*)&Bs[kk][tx << 2];
            acc[0][0] += a4.x * b4.x; acc[0][1] += a4.x * b4.y; acc[0][2] += a4.x * b4.z; acc[0][3] += a4.x * b4.w;
            acc[1][0] += a4.y * b4.x; acc[1][1] += a4.y * b4.y; acc[1][2] += a4.y * b4.z; acc[1][3] += a4.y * b4.w;
            acc[2][0] += a4.z * b4.x; acc[2][1] += a4.z * b4.y; acc[2][2] += a4.z * b4.z; acc[2][3] += a4.z * b4.w;
            acc[3][0] += a4.w * b4.x; acc[3][1] += a4.w * b4.y; acc[3][2] += a4.w * b4.z; acc[3][3] += a4.w * b4.w;
        }
        __syncthreads();
        af += 16;
        boff += (size_t)16 * N;
    }
#pragma unroll
    for (int i = 0; i < 4; i++) {
        int r = m0 + (ty << 2) + i;
        if (r >= cnt) continue;
        int tok = lp ? lp[r] : r;
        const float* rrow = resid ? (resid + (size_t)tok * N + n0 + (tx << 2)) : nullptr;
#pragma unroll
        for (int j = 0; j < 4; j++) {
            int col = n0 + (tx << 2) + j;
            float bval = bfm ? us2f(((const unsigned short*)bias)[e * N + col])
                             : ((const float*)bias)[(size_t)e * N + col];
            float v = acc[i][j] + bval;
            if (rrow) v += rrow[j];
            if (relu) v = fmaxf(v, 0.f);
            C[(size_t)tok * N + col] = v;
        }
    }
}

// ---------------------------------------------------------------------------
// Causal flash attention, one wave per query row. lane == head-dim (DH=64).
// j=0 peeled so no exp() ever sees a +-huge argument.
// ---------------------------------------------------------------------------
__global__ __launch_bounds__(256) void attn_flash(const float* __restrict__ q,
    const float* __restrict__ k, const float* __restrict__ v, float* __restrict__ outp)
{
    const int gw = (blockIdx.x * 256 + threadIdx.x) >> 6;  // global wave id
    const int lane = threadIdx.x & 63;
    const int t  = gw & (TT - 1);
    const int bh = gw >> 11;                 // TT == 2048
    const int b = bh >> 4, h = bh & 15;      // H == 16
    const size_t headbase = (size_t)b * TT * D + (size_t)h * DH;

    const float qd = q[headbase + (size_t)t * D + lane] * 0.125f;  // 1/sqrt(64)
    const float* kp = k + headbase + lane;
    const float* vp = v + headbase + lane;

    // peeled j = 0
    float s = qd * kp[0];
#pragma unroll
    for (int msk = 32; msk > 0; msk >>= 1) s += __shfl_xor(s, msk, 64);
    float m = s, l = 1.f, oacc = vp[0];

    for (int j = 1; j <= t; ++j) {
        s = qd * kp[(size_t)j * D];
#pragma unroll
        for (int msk = 32; msk > 0; msk >>= 1) s += __shfl_xor(s, msk, 64);
        float vj = vp[(size_t)j * D];
        float nm = fmaxf(m, s);
        float sc = __expf(m - nm);
        float p  = __expf(s - nm);
        l = l * sc + p;
        oacc = oacc * sc + p * vj;
        m = nm;
    }
    outp[headbase + (size_t)t * D + lane] = oacc / l;
}

// ---------------------------------------------------------------------------
// LayerNorm over D=1024. a: f32; optional f32 residual; g/b in input dtype
// (runtime flag); out f32. In-place (out==a or out==resid) is safe: all reads
// precede writes (block owns the row).
// ---------------------------------------------------------------------------
__global__ __launch_bounds__(256) void layernorm_k(const float* __restrict__ a,
    const float* __restrict__ resid, const void* __restrict__ g_,
    const void* __restrict__ b_, float* __restrict__ out,
    const int* __restrict__ meta)
{
    const int bfm = meta[4];
    const int row = blockIdx.x;
    const int tid = threadIdx.x;
    float vals[4];
    float s = 0.f, s2 = 0.f;
#pragma unroll
    for (int i = 0; i < 4; i++) {
        int idx = tid + (i << 8);
        float v = a[(size_t)row * D + idx];
        if (resid) v += resid[(size_t)row * D + idx];
        vals[i] = v; s += v; s2 += v * v;
    }
#pragma unroll
    for (int msk = 32; msk > 0; msk >>= 1) {
        s  += __shfl_xor(s,  msk, 64);
        s2 += __shfl_xor(s2, msk, 64);
    }
    __shared__ float red[2][4];
    if ((tid & 63) == 0) { red[0][tid >> 6] = s; red[1][tid >> 6] = s2; }
    __syncthreads();
    s  = red[0][0] + red[0][1] + red[0][2] + red[0][3];
    s2 = red[1][0] + red[1][1] + red[1][2] + red[1][3];
    const float mu = s * (1.f / D);
    const float var = s2 * (1.f / D) - mu * mu;
    const float rs = rsqrtf(var + 1e-5f);
#pragma unroll
    for (int i = 0; i < 4; i++) {
        int idx = tid + (i << 8);
        float gg = bfm ? us2f(((const unsigned short*)g_)[idx]) : ((const float*)g_)[idx];
        float bb = bfm ? us2f(((const unsigned short*)b_)[idx]) : ((const float*)b_)[idx];
        out[(size_t)row * D + idx] = (vals[i] - mu) * rs * gg + bb;
    }
}

// ---------------------------------------------------------------------------
// Top-1 gate in fp32 + bucket scatter. One wave per token.
// ---------------------------------------------------------------------------
__global__ __launch_bounds__(256) void gate_k(const float* __restrict__ x1,
    const void* __restrict__ Wg, const void* __restrict__ bg,
    int* __restrict__ cnt, int* __restrict__ list, const int* __restrict__ meta)
{
    const int bfm = meta[4];
    const int tok = (blockIdx.x * 256 + threadIdx.x) >> 6;
    const int lane = threadIdx.x & 63;
    const float* xr = x1 + (size_t)tok * D;
    float s0 = 0.f, s1 = 0.f, s2 = 0.f, s3 = 0.f;
    for (int d = lane; d < D; d += 64) {
        float xv = xr[d];
        float w0, w1, w2, w3;
        if (bfm) {
            ushort4 wu = ((const ushort4*)Wg)[d];   // row d of (D, E=4)
            w0 = us2f(wu.x); w1 = us2f(wu.y); w2 = us2f(wu.z); w3 = us2f(wu.w);
        } else {
            float4 wf = ((const float4*)Wg)[d];
            w0 = wf.x; w1 = wf.y; w2 = wf.z; w3 = wf.w;
        }
        s0 += xv * w0; s1 += xv * w1; s2 += xv * w2; s3 += xv * w3;
    }
#pragma unroll
    for (int msk = 32; msk > 0; msk >>= 1) {
        s0 += __shfl_xor(s0, msk, 64); s1 += __shfl_xor(s1, msk, 64);
        s2 += __shfl_xor(s2, msk, 64); s3 += __shfl_xor(s3, msk, 64);
    }
    if (lane == 0) {
        float g0, g1, g2, g3;
        if (bfm) {
            g0 = us2f(((const unsigned short*)bg)[0]); g1 = us2f(((const unsigned short*)bg)[1]);
            g2 = us2f(((const unsigned short*)bg)[2]); g3 = us2f(((const unsigned short*)bg)[3]);
        } else {
            g0 = ((const float*)bg)[0]; g1 = ((const float*)bg)[1];
            g2 = ((const float*)bg)[2]; g3 = ((const float*)bg)[3];
        }
        float b0 = s0 + g0, b1 = s1 + g1, b2 = s2 + g2, b3 = s3 + g3;
        int bi = 0; float best = b0;
        if (b1 > best) { best = b1; bi = 1; }   // strict > == jnp.argmax first-max
        if (b2 > best) { best = b2; bi = 2; }
        if (b3 > best) { best = b3; bi = 3; }
        int slot = atomicAdd(&cnt[bi], 1);
        list[bi * NTOK + slot] = tok;
    }
}

// ---------------------------------------------------------------------------
// Workspace (~80 MB): xf(NE) buf0..buf3(4*NE) | meta(16 ints) list(E*NTOK)
//   xf:   x as f32 -> x1 (post-LN1, in-place)
//   buf0: q -> attn_out -> h[0:NE)
//   buf1: k -> h[NE:2NE)       buf2: v -> h[2NE:3NE)    buf3: attn -> h[3NE:4NE)
//   resid2 staged f32 in d_out (reference output dtype = float32);
//   LN2 in-place on d_out.
// ---------------------------------------------------------------------------
extern "C" void kernel_launch(void* const* d_in, const int* in_sizes, int n_in,
                              void* d_out, int out_size, void* d_ws, size_t ws_size,
                              hipStream_t stream)
{
    const void* x  = d_in[0];
    // d_in[1] = causal mask (guaranteed tril) -- hard-coded, not read
    const void* Wq = d_in[2];  const void* bq = d_in[3];
    const void* Wk = d_in[4];  const void* bk = d_in[5];
    const void* Wv = d_in[6];  const void* bv = d_in[7];
    const void* Wo = d_in[8];  const void* bo = d_in[9];
    const void* g1 = d_in[10]; const void* b1 = d_in[11];
    const void* Wg = d_in[12]; const void* bg = d_in[13];
    const void* W1e = d_in[14]; const void* b1e = d_in[15];
    const void* W2e = d_in[16]; const void* b2e = d_in[17];
    const void* g2 = d_in[18]; const void* b2 = d_in[19];

    const size_t NE = (size_t)NTOK * D;  // 4M elems
    float* ws   = (float*)d_ws;
    float* xf   = ws;                    // x (f32) -> x1
    float* buf0 = ws + 1 * NE;
    float* buf1 = ws + 2 * NE;
    float* buf2 = ws + 3 * NE;
    float* buf3 = ws + 4 * NE;
    float* hbuf = buf0;                  // 4*NE f32 = NTOK*FF
    int* meta = (int*)(ws + 5 * NE);     // [0..3]=cnt, [4]=dtype flag
    int* list = meta + 16;               // E * NTOK slots
    float* outf = (float*)d_out;         // f32 output buffer

    // dtype probe + cnt zero-init
    probe_k<<<1, 64, 0, stream>>>((const unsigned*)x, meta);

    // x -> f32
    convert_k<<<(int)(NE / 4 / 256), 256, 0, stream>>>(x, xf, meta);

    // QKV projections
    dim3 gqkv(D / 64, NTOK / 64, 1);
    sgemm_k<<<gqkv, 256, 0, stream>>>(xf, Wq, bq, buf0, nullptr, nullptr, nullptr, meta, NTOK, D, D, 0);
    sgemm_k<<<gqkv, 256, 0, stream>>>(xf, Wk, bk, buf1, nullptr, nullptr, nullptr, meta, NTOK, D, D, 0);
    sgemm_k<<<gqkv, 256, 0, stream>>>(xf, Wv, bv, buf2, nullptr, nullptr, nullptr, meta, NTOK, D, D, 0);

    // causal attention (one wave per query row)
    attn_flash<<<(BSZ * H * TT) / 4, 256, 0, stream>>>(buf0, buf1, buf2, buf3);

    // output projection (attn @ Wo) -> buf0, then LN1(attn_out + x) -> x1 into xf
    sgemm_k<<<gqkv, 256, 0, stream>>>(buf3, Wo, bo, buf0, nullptr, nullptr, nullptr, meta, NTOK, D, D, 0);
    layernorm_k<<<NTOK, 256, 0, stream>>>(buf0, xf, g1, b1, xf, meta);

    // top-1 gate + expert bucketing (fp32 x1)
    gate_k<<<NTOK / 4, 256, 0, stream>>>(xf, Wg, bg, meta, list, meta);

    // MoE FFN (selected expert only), gather/scatter GEMMs
    dim3 gf1(FF / 64, NTOK / 64, E);
    sgemm_k<<<gf1, 256, 0, stream>>>(xf, W1e, b1e, hbuf, nullptr, list, meta, meta, NTOK, FF, D, 1);
    dim3 gf2(D / 64, NTOK / 64, E);
    sgemm_k<<<gf2, 256, 0, stream>>>(hbuf, W2e, b2e, outf, xf, list, meta, meta, NTOK, D, FF, 0);

    // LN2 in-place on d_out (f32 in, f32 out)
    layernorm_k<<<NTOK, 256, 0, stream>>>(outf, nullptr, g2, b2, outf, meta);
}

// Round 5
// 2441.136 us; speedup vs baseline: 2.7090x; 2.7090x over previous
//
#include <hip/hip_runtime.h>
#include <hip/hip_bf16.h>

// Problem constants (reference file)
#define D   1024
#define H   16
#define DH  64
#define FF  4096
#define E   4
#define BSZ 2
#define TT  2048
#define NTOK (BSZ*TT)   // 4096 tokens

typedef __hip_bfloat16 bf16;

__device__ __forceinline__ float us2f(unsigned short u) {
    return __uint_as_float(((unsigned int)u) << 16);  // bf16 -> f32 is exact
}

// ---------------------------------------------------------------------------
// Dtype probe (R3-verified: correctly detected f32 inputs). Zero-inits cnt[].
// ---------------------------------------------------------------------------
__global__ __launch_bounds__(64) void probe_k(const unsigned* __restrict__ xw,
                                              int* __restrict__ meta) {
    const int lane = threadIdx.x;
    int wild = 0;
    for (int i = 0; i < 32; i++) {
        unsigned u = xw[lane * 32 + i];
        unsigned lo = u & 0xFFFFu;
        if ((lo & 0x7F80u) >= 0x5A00u) wild++;
    }
#pragma unroll
    for (int m = 32; m > 0; m >>= 1) wild += __shfl_xor(wild, m, 64);
    if (lane == 0) meta[4] = (wild < 64) ? 1 : 0;   // 1 = bf16 inputs, 0 = f32
    if (lane < 4) meta[lane] = 0;                   // expert counters
}

// ---------------------------------------------------------------------------
// x -> f32 staging (dual dtype), 4 elems/thread
// ---------------------------------------------------------------------------
__global__ __launch_bounds__(256) void convert_k(const void* __restrict__ in,
                                                 float* __restrict__ out,
                                                 const int* __restrict__ meta) {
    const int i = blockIdx.x * 256 + threadIdx.x;
    if (meta[4]) {
        ushort4 u = ((const ushort4*)in)[i];
        ((float4*)out)[i] = make_float4(us2f(u.x), us2f(u.y), us2f(u.z), us2f(u.w));
    } else {
        ((float4*)out)[i] = ((const float4*)in)[i];
    }
}

// ---------------------------------------------------------------------------
// Tiled GEMM: C[M,N] = A[M,K](f32 ws) * B[K,N](input dtype) + bias(input dtype)
//   64x64 tile, BK=16, 256 threads, 4x4 micro-tile, fp32 accumulate.
// ---------------------------------------------------------------------------
__global__ __launch_bounds__(256) void sgemm_k(
    const float* __restrict__ A, const void* __restrict__ Bw,
    const void* __restrict__ bias, float* __restrict__ C,
    const float* __restrict__ resid, const int* __restrict__ rowlist,
    const int* __restrict__ rowcnt, const int* __restrict__ meta,
    int M, int N, int K, int relu)
{
    const int bfm = meta[4];
    const int e = blockIdx.z;
    const int cnt = rowcnt ? rowcnt[e] : M;
    const int m0 = blockIdx.y * 64;
    if (m0 >= cnt) return;
    const int n0 = blockIdx.x * 64;
    const int* lp = rowlist ? (rowlist + e * NTOK) : nullptr;

    __shared__ float As[16][64];
    __shared__ float Bs[16][64];

    const int tid = threadIdx.x;
    const int ar = tid >> 2;
    const int ac = (tid & 3) << 2;
    const int r_a = m0 + ar;
    const bool avalid = (r_a < cnt);
    const int atok = avalid ? (lp ? lp[r_a] : r_a) : 0;
    const float* af = A + (size_t)atok * K + ac;
    const int br = tid >> 4;
    const int bc = (tid & 15) << 2;
    size_t boff = (size_t)e * K * N + (size_t)br * N + (n0 + bc);

    const int tx = tid & 15, ty = tid >> 4;
    float acc[4][4];
#pragma unroll
    for (int i = 0; i < 4; i++)
#pragma unroll
        for (int j = 0; j < 4; j++) acc[i][j] = 0.f;

    for (int k0 = 0; k0 < K; k0 += 16) {
        float4 av = make_float4(0.f, 0.f, 0.f, 0.f);
        if (avalid) av = *(const float4*)af;
        float4 bv;
        if (bfm) {
            ushort4 bu = *(const ushort4*)((const unsigned short*)Bw + boff);
            bv = make_float4(us2f(bu.x), us2f(bu.y), us2f(bu.z), us2f(bu.w));
        } else {
            bv = *(const float4*)((const float*)Bw + boff);
        }
        As[ac + 0][ar] = av.x; As[ac + 1][ar] = av.y;
        As[ac + 2][ar] = av.z; As[ac + 3][ar] = av.w;
        *(float4*)&Bs[br][bc] = bv;
        __syncthreads();
#pragma unroll
        for (int kk = 0; kk < 16; kk++) {
            float4 a4 = *(const float4*)&As[kk][ty << 2];
            float4 b4 = *(const float4*)&Bs[kk][tx << 2];
            acc[0][0] += a4.x * b4.x; acc[0][1] += a4.x * b4.y; acc[0][2] += a4.x * b4.z; acc[0][3] += a4.x * b4.w;
            acc[1][0] += a4.y * b4.x; acc[1][1] += a4.y * b4.y; acc[1][2] += a4.y * b4.z; acc[1][3] += a4.y * b4.w;
            acc[2][0] += a4.z * b4.x; acc[2][1] += a4.z * b4.y; acc[2][2] += a4.z * b4.z; acc[2][3] += a4.z * b4.w;
            acc[3][0] += a4.w * b4.x; acc[3][1] += a4.w * b4.y; acc[3][2] += a4.w * b4.z; acc[3][3] += a4.w * b4.w;
        }
        __syncthreads();
        af += 16;
        boff += (size_t)16 * N;
    }
#pragma unroll
    for (int i = 0; i < 4; i++) {
        int r = m0 + (ty << 2) + i;
        if (r >= cnt) continue;
        int tok = lp ? lp[r] : r;
        const float* rrow = resid ? (resid + (size_t)tok * N + n0 + (tx << 2)) : nullptr;
#pragma unroll
        for (int j = 0; j < 4; j++) {
            int col = n0 + (tx << 2) + j;
            float bval = bfm ? us2f(((const unsigned short*)bias)[e * N + col])
                             : ((const float*)bias)[(size_t)e * N + col];
            float v = acc[i][j] + bval;
            if (rrow) v += rrow[j];
            if (relu) v = fmaxf(v, 0.f);
            C[(size_t)tok * N + col] = v;
        }
    }
}

// ---------------------------------------------------------------------------
// Tiled causal flash attention. One 256-thread block per (64-query tile, b, h).
// K/V tiles of 64 in LDS; S=Q.K^T and O+=P.V as 64x64x64 register GEMMs
// (4x4 micro-tile, same pattern as sgemm_k). Online softmax state in LDS.
// P round-trips through the K LDS buffer (safe: sync separates phases).
// exp args are clamped at -80 (no -1e30 into __expf -- R1 NaN lesson).
// ---------------------------------------------------------------------------
__global__ __launch_bounds__(256) void attn_tile(const float* __restrict__ q,
    const float* __restrict__ k, const float* __restrict__ v, float* __restrict__ outp)
{
    const int qi = (int)gridDim.x - 1 - (int)blockIdx.x;  // heavy tiles first
    const int bh = blockIdx.y;
    const int b = bh >> 4, h = bh & 15;
    const size_t base = (size_t)b * TT * D + (size_t)h * DH;

    __shared__ float Qs[64][64];    // [d][q]
    __shared__ float KPs[64][64];   // K as [d][k], then P as [kk][q]
    __shared__ float Vs[64][64];    // [kk][d]
    __shared__ float red[64][17];   // row reductions (+1 pad: kills 32-way conflict)
    __shared__ float mrow[64], lrow[64], arow[64];

    const int tid = threadIdx.x;
    const int tx = tid & 15, ty = tid >> 4;
    const int tx4 = tx << 2, ty4 = ty << 2;
    const int sr = tid >> 2;            // staging row (0..63)
    const int sc = (tid & 3) << 4;      // staging d-segment base (0,16,32,48)

    // stage Q tile, transposed, pre-scaled by 1/sqrt(DH)
    {
        const float* qrow = q + base + (size_t)(qi * 64 + sr) * D;
#pragma unroll
        for (int r = 0; r < 4; r++) {
            int d0 = sc + (r << 2);
            float4 qv = *(const float4*)(qrow + d0);
            Qs[d0 + 0][sr] = qv.x * 0.125f; Qs[d0 + 1][sr] = qv.y * 0.125f;
            Qs[d0 + 2][sr] = qv.z * 0.125f; Qs[d0 + 3][sr] = qv.w * 0.125f;
        }
    }
    if (tid < 64) { mrow[tid] = -1e30f; lrow[tid] = 0.f; }

    float o[4][4];
#pragma unroll
    for (int i = 0; i < 4; i++)
#pragma unroll
        for (int j = 0; j < 4; j++) o[i][j] = 0.f;

    for (int kt = 0; kt <= qi; ++kt) {
        __syncthreads();   // prev PV reads done; KPs/Vs reusable; Q staged (1st iter)
        // stage K tile (transposed -> [d][k]) and V tile ([kk][d])
        {
            const float* krow = k + base + (size_t)(kt * 64 + sr) * D;
            const float* vrow = v + base + (size_t)(kt * 64 + sr) * D;
#pragma unroll
            for (int r = 0; r < 4; r++) {
                int d0 = sc + (r << 2);
                float4 kv = *(const float4*)(krow + d0);
                KPs[d0 + 0][sr] = kv.x; KPs[d0 + 1][sr] = kv.y;
                KPs[d0 + 2][sr] = kv.z; KPs[d0 + 3][sr] = kv.w;
                *(float4*)&Vs[sr][d0] = *(const float4*)(vrow + d0);
            }
        }
        __syncthreads();

        // S = Q.K^T  (s[i][j] = S[ty4+i][tx4+j])
        float s[4][4];
#pragma unroll
        for (int i = 0; i < 4; i++)
#pragma unroll
            for (int j = 0; j < 4; j++) s[i][j] = 0.f;
        for (int d = 0; d < 64; d++) {
            float4 a4 = *(const float4*)&Qs[d][ty4];
            float4 b4 = *(const float4*)&KPs[d][tx4];
            s[0][0] += a4.x * b4.x; s[0][1] += a4.x * b4.y; s[0][2] += a4.x * b4.z; s[0][3] += a4.x * b4.w;
            s[1][0] += a4.y * b4.x; s[1][1] += a4.y * b4.y; s[1][2] += a4.y * b4.z; s[1][3] += a4.y * b4.w;
            s[2][0] += a4.z * b4.x; s[2][1] += a4.z * b4.y; s[2][2] += a4.z * b4.z; s[2][3] += a4.z * b4.w;
            s[3][0] += a4.w * b4.x; s[3][1] += a4.w * b4.y; s[3][2] += a4.w * b4.z; s[3][3] += a4.w * b4.w;
        }
        // causal mask on diagonal tile (local q < local k -> masked)
        if (kt == qi) {
#pragma unroll
            for (int i = 0; i < 4; i++)
#pragma unroll
                for (int j = 0; j < 4; j++)
                    if (ty4 + i < tx4 + j) s[i][j] = -1e30f;
        }
        // partial row max
#pragma unroll
        for (int i = 0; i < 4; i++)
            red[ty4 + i][tx] = fmaxf(fmaxf(s[i][0], s[i][1]), fmaxf(s[i][2], s[i][3]));
        __syncthreads();   // also: all S-GEMM reads of KPs(K) complete after this
        if (tid < 64) {
            float rm = red[tid][0];
#pragma unroll
            for (int t = 1; t < 16; t++) rm = fmaxf(rm, red[tid][t]);
            float mo = mrow[tid];
            float mn = fmaxf(mo, rm);
            arow[tid] = (mo < -9e29f) ? 0.f : __expf(mo - mn);
            mrow[tid] = mn;
        }
        __syncthreads();
        // p = exp(s - m); write P -> KPs[kk][q]; partial row sums
#pragma unroll
        for (int i = 0; i < 4; i++) {
            float mi = mrow[ty4 + i];
            float rs = 0.f;
#pragma unroll
            for (int j = 0; j < 4; j++) {
                float p = __expf(fmaxf(s[i][j] - mi, -80.f));  // masked -> ~1.8e-35
                KPs[tx4 + j][ty4 + i] = p;
                rs += p;
            }
            red[ty4 + i][tx] = rs;
        }
        __syncthreads();
        if (tid < 64) {
            float rs = 0.f;
#pragma unroll
            for (int t = 0; t < 16; t++) rs += red[tid][t];
            lrow[tid] = lrow[tid] * arow[tid] + rs;
        }
        // rescale O, then O += P.V
        {
            float a0 = arow[ty4 + 0], a1 = arow[ty4 + 1], a2 = arow[ty4 + 2], a3 = arow[ty4 + 3];
#pragma unroll
            for (int j = 0; j < 4; j++) { o[0][j] *= a0; o[1][j] *= a1; o[2][j] *= a2; o[3][j] *= a3; }
        }
        for (int kk = 0; kk < 64; kk++) {
            float4 a4 = *(const float4*)&KPs[kk][ty4];
            float4 b4 = *(const float4*)&Vs[kk][tx4];
            o[0][0] += a4.x * b4.x; o[0][1] += a4.x * b4.y; o[0][2] += a4.x * b4.z; o[0][3] += a4.x * b4.w;
            o[1][0] += a4.y * b4.x; o[1][1] += a4.y * b4.y; o[1][2] += a4.y * b4.z; o[1][3] += a4.y * b4.w;
            o[2][0] += a4.z * b4.x; o[2][1] += a4.z * b4.y; o[2][2] += a4.z * b4.z; o[2][3] += a4.z * b4.w;
            o[3][0] += a4.w * b4.x; o[3][1] += a4.w * b4.y; o[3][2] += a4.w * b4.z; o[3][3] += a4.w * b4.w;
        }
    }
    __syncthreads();   // lrow final
#pragma unroll
    for (int i = 0; i < 4; i++) {
        float inv = 1.f / lrow[ty4 + i];
        float4 ov = make_float4(o[i][0] * inv, o[i][1] * inv, o[i][2] * inv, o[i][3] * inv);
        *(float4*)&outp[base + (size_t)(qi * 64 + ty4 + i) * D + tx4] = ov;
    }
}

// ---------------------------------------------------------------------------
// LayerNorm over D=1024 (in-place safe).
// ---------------------------------------------------------------------------
__global__ __launch_bounds__(256) void layernorm_k(const float* __restrict__ a,
    const float* __restrict__ resid, const void* __restrict__ g_,
    const void* __restrict__ b_, float* __restrict__ out,
    const int* __restrict__ meta)
{
    const int bfm = meta[4];
    const int row = blockIdx.x;
    const int tid = threadIdx.x;
    float vals[4];
    float s = 0.f, s2 = 0.f;
#pragma unroll
    for (int i = 0; i < 4; i++) {
        int idx = tid + (i << 8);
        float v = a[(size_t)row * D + idx];
        if (resid) v += resid[(size_t)row * D + idx];
        vals[i] = v; s += v; s2 += v * v;
    }
#pragma unroll
    for (int msk = 32; msk > 0; msk >>= 1) {
        s  += __shfl_xor(s,  msk, 64);
        s2 += __shfl_xor(s2, msk, 64);
    }
    __shared__ float red[2][4];
    if ((tid & 63) == 0) { red[0][tid >> 6] = s; red[1][tid >> 6] = s2; }
    __syncthreads();
    s  = red[0][0] + red[0][1] + red[0][2] + red[0][3];
    s2 = red[1][0] + red[1][1] + red[1][2] + red[1][3];
    const float mu = s * (1.f / D);
    const float var = s2 * (1.f / D) - mu * mu;
    const float rs = rsqrtf(var + 1e-5f);
#pragma unroll
    for (int i = 0; i < 4; i++) {
        int idx = tid + (i << 8);
        float gg = bfm ? us2f(((const unsigned short*)g_)[idx]) : ((const float*)g_)[idx];
        float bb = bfm ? us2f(((const unsigned short*)b_)[idx]) : ((const float*)b_)[idx];
        out[(size_t)row * D + idx] = (vals[i] - mu) * rs * gg + bb;
    }
}

// ---------------------------------------------------------------------------
// Top-1 gate in fp32 + bucket scatter. One wave per token.
// ---------------------------------------------------------------------------
__global__ __launch_bounds__(256) void gate_k(const float* __restrict__ x1,
    const void* __restrict__ Wg, const void* __restrict__ bg,
    int* __restrict__ cnt, int* __restrict__ list, const int* __restrict__ meta)
{
    const int bfm = meta[4];
    const int tok = (blockIdx.x * 256 + threadIdx.x) >> 6;
    const int lane = threadIdx.x & 63;
    const float* xr = x1 + (size_t)tok * D;
    float s0 = 0.f, s1 = 0.f, s2 = 0.f, s3 = 0.f;
    for (int d = lane; d < D; d += 64) {
        float xv = xr[d];
        float w0, w1, w2, w3;
        if (bfm) {
            ushort4 wu = ((const ushort4*)Wg)[d];
            w0 = us2f(wu.x); w1 = us2f(wu.y); w2 = us2f(wu.z); w3 = us2f(wu.w);
        } else {
            float4 wf = ((const float4*)Wg)[d];
            w0 = wf.x; w1 = wf.y; w2 = wf.z; w3 = wf.w;
        }
        s0 += xv * w0; s1 += xv * w1; s2 += xv * w2; s3 += xv * w3;
    }
#pragma unroll
    for (int msk = 32; msk > 0; msk >>= 1) {
        s0 += __shfl_xor(s0, msk, 64); s1 += __shfl_xor(s1, msk, 64);
        s2 += __shfl_xor(s2, msk, 64); s3 += __shfl_xor(s3, msk, 64);
    }
    if (lane == 0) {
        float g0, g1, g2, g3;
        if (bfm) {
            g0 = us2f(((const unsigned short*)bg)[0]); g1 = us2f(((const unsigned short*)bg)[1]);
            g2 = us2f(((const unsigned short*)bg)[2]); g3 = us2f(((const unsigned short*)bg)[3]);
        } else {
            g0 = ((const float*)bg)[0]; g1 = ((const float*)bg)[1];
            g2 = ((const float*)bg)[2]; g3 = ((const float*)bg)[3];
        }
        float b0 = s0 + g0, b1 = s1 + g1, b2 = s2 + g2, b3 = s3 + g3;
        int bi = 0; float best = b0;
        if (b1 > best) { best = b1; bi = 1; }
        if (b2 > best) { best = b2; bi = 2; }
        if (b3 > best) { best = b3; bi = 3; }
        int slot = atomicAdd(&cnt[bi], 1);
        list[bi * NTOK + slot] = tok;
    }
}

// ---------------------------------------------------------------------------
extern "C" void kernel_launch(void* const* d_in, const int* in_sizes, int n_in,
                              void* d_out, int out_size, void* d_ws, size_t ws_size,
                              hipStream_t stream)
{
    const void* x  = d_in[0];
    const void* Wq = d_in[2];  const void* bq = d_in[3];
    const void* Wk = d_in[4];  const void* bk = d_in[5];
    const void* Wv = d_in[6];  const void* bv = d_in[7];
    const void* Wo = d_in[8];  const void* bo = d_in[9];
    const void* g1 = d_in[10]; const void* b1 = d_in[11];
    const void* Wg = d_in[12]; const void* bg = d_in[13];
    const void* W1e = d_in[14]; const void* b1e = d_in[15];
    const void* W2e = d_in[16]; const void* b2e = d_in[17];
    const void* g2 = d_in[18]; const void* b2 = d_in[19];

    const size_t NE = (size_t)NTOK * D;  // 4M elems
    float* ws   = (float*)d_ws;
    float* xf   = ws;                    // x (f32) -> x1
    float* buf0 = ws + 1 * NE;
    float* buf1 = ws + 2 * NE;
    float* buf2 = ws + 3 * NE;
    float* buf3 = ws + 4 * NE;
    float* hbuf = buf0;                  // 4*NE f32 = NTOK*FF
    int* meta = (int*)(ws + 5 * NE);     // [0..3]=cnt, [4]=dtype flag
    int* list = meta + 16;
    float* outf = (float*)d_out;

    probe_k<<<1, 64, 0, stream>>>((const unsigned*)x, meta);
    convert_k<<<(int)(NE / 4 / 256), 256, 0, stream>>>(x, xf, meta);

    dim3 gqkv(D / 64, NTOK / 64, 1);
    sgemm_k<<<gqkv, 256, 0, stream>>>(xf, Wq, bq, buf0, nullptr, nullptr, nullptr, meta, NTOK, D, D, 0);
    sgemm_k<<<gqkv, 256, 0, stream>>>(xf, Wk, bk, buf1, nullptr, nullptr, nullptr, meta, NTOK, D, D, 0);
    sgemm_k<<<gqkv, 256, 0, stream>>>(xf, Wv, bv, buf2, nullptr, nullptr, nullptr, meta, NTOK, D, D, 0);

    // tiled causal flash attention: (q-tiles, b*h) blocks
    attn_tile<<<dim3(TT / 64, BSZ * H), 256, 0, stream>>>(buf0, buf1, buf2, buf3);

    sgemm_k<<<gqkv, 256, 0, stream>>>(buf3, Wo, bo, buf0, nullptr, nullptr, nullptr, meta, NTOK, D, D, 0);
    layernorm_k<<<NTOK, 256, 0, stream>>>(buf0, xf, g1, b1, xf, meta);

    gate_k<<<NTOK / 4, 256, 0, stream>>>(xf, Wg, bg, meta, list, meta);

    dim3 gf1(FF / 64, NTOK / 64, E);
    sgemm_k<<<gf1, 256, 0, stream>>>(xf, W1e, b1e, hbuf, nullptr, list, meta, meta, NTOK, FF, D, 1);
    dim3 gf2(D / 64, NTOK / 64, E);
    sgemm_k<<<gf2, 256, 0, stream>>>(hbuf, W2e, b2e, outf, xf, list, meta, meta, NTOK, D, FF, 0);

    layernorm_k<<<NTOK, 256, 0, stream>>>(outf, nullptr, g2, b2, outf, meta);
}